// Round 1
// baseline (155.712 us; speedup 1.0000x reference)
//
#include <hip/hip_runtime.h>
#include <stdint.h>

static constexpr int Mrows = 16384;   // B*N = 64*256
static constexpr int Kdim  = 1024;    // L
static constexpr int Ncols = 512;     // OUT

typedef __attribute__((ext_vector_type(8))) short bf16x8;
typedef __attribute__((ext_vector_type(4))) float f32x4;

__device__ __forceinline__ unsigned short f2bf(float f) {
  unsigned u = __builtin_bit_cast(unsigned, f);
  u += 0x7FFFu + ((u >> 16) & 1u);          // RNE
  return (unsigned short)(u >> 16);
}
__device__ __forceinline__ unsigned f2bf2(float lo, float hi) {
  unsigned ul = __builtin_bit_cast(unsigned, lo);
  unsigned uh = __builtin_bit_cast(unsigned, hi);
  ul += 0x7FFFu + ((ul >> 16) & 1u);
  uh += 0x7FFFu + ((uh >> 16) & 1u);
  return (ul >> 16) | (uh & 0xFFFF0000u);
}

// ---------------------------------------------------------------------------
// Kernel 1: Wt[n][k] = bf16( 0.5*(W_in[k][n] + W_out[k][n]) + W_root[k][n] )
// 32x32 tile transpose through LDS; coalesced float4 reads, 8B ushort4 writes.
// ---------------------------------------------------------------------------
__global__ __launch_bounds__(256) void combine_w(
    const float* __restrict__ Win, const float* __restrict__ Wout,
    const float* __restrict__ Wroot, unsigned short* __restrict__ Wt)
{
  __shared__ unsigned short lds[32 * 36];   // stride 36 keeps 8B alignment, no pow2 conflicts
  const int bid = blockIdx.x;
  const int tk0 = (bid & 31) * 32;          // 1024/32 = 32 K-tiles
  const int tn0 = (bid >> 5) * 32;          // 512/32  = 16 N-tiles
  const int t = threadIdx.x;
  {
    const int k  = t >> 3;                  // 0..31
    const int nq = (t & 7) * 4;             // 0,4,..,28
    const int gi = (tk0 + k) * Ncols + tn0 + nq;
    const float4 wi = *(const float4*)(Win + gi);
    const float4 wo = *(const float4*)(Wout + gi);
    const float4 wr = *(const float4*)(Wroot + gi);
    lds[(nq + 0) * 36 + k] = f2bf(0.5f * (wi.x + wo.x) + wr.x);
    lds[(nq + 1) * 36 + k] = f2bf(0.5f * (wi.y + wo.y) + wr.y);
    lds[(nq + 2) * 36 + k] = f2bf(0.5f * (wi.z + wo.z) + wr.z);
    lds[(nq + 3) * 36 + k] = f2bf(0.5f * (wi.w + wo.w) + wr.w);
  }
  __syncthreads();
  {
    const int n  = t >> 3;                  // 0..31
    const int k8 = (t & 7) * 4;             // 0,4,..,28
    const ushort4 v = *(const ushort4*)&lds[n * 36 + k8];
    *(ushort4*)(Wt + (size_t)(tn0 + n) * Kdim + tk0 + k8) = v;
  }
}

// ---------------------------------------------------------------------------
// Kernel 2: Y[16384][512] = X[16384][1024] @ W + bias, bf16 MFMA 16x16x32.
// Block tile 128x128, BK=32, 4 waves in 2x2, each wave 64x64 (4x4 MFMA tiles).
// LDS tiles stored [row][k] with stride 40 shorts (80B) -> conflict-free
// ds_read_b128 fragments. fp32 x converted to bf16 in registers at staging.
// Register prefetch of next K-slice issued before the MFMA burst.
// ---------------------------------------------------------------------------
__global__ __launch_bounds__(256) void gemm_fused(
    const float* __restrict__ X, const unsigned short* __restrict__ Wt,
    const float* __restrict__ b_in, const float* __restrict__ b_out,
    const float* __restrict__ b_root, float* __restrict__ Y)
{
  __shared__ short Asl[128 * 40];
  __shared__ short Bsl[128 * 40];

  const int bid = blockIdx.x;
  const int m0 = (bid & 127) * 128;   // m fast: the 4 n-blocks of one m-panel
  const int n0 = (bid >> 7) * 128;    // share bid%8 -> same XCD -> L2 reuse of x

  const int t    = threadIdx.x;
  const int lane = t & 63;
  const int wid  = t >> 6;
  const int wm   = wid >> 1;
  const int wn   = wid & 1;
  const int quad = lane >> 4;
  const int lm   = lane & 15;

  // staging: thread -> (row 0..127, half 0|1); 16 elems (32B LDS) per thread
  const int sr = t >> 1;
  const int sh = t & 1;
  const float*          xp = X  + (size_t)(m0 + sr) * Kdim + sh * 16;
  const unsigned short* wp = Wt + (size_t)(n0 + sr) * Kdim + sh * 16;
  const int sbase = sr * 40 + sh * 16;

  f32x4 acc[4][4] = {};

  // preload K-slice 0
  float4 a0 = *(const float4*)(xp + 0);
  float4 a1 = *(const float4*)(xp + 4);
  float4 a2 = *(const float4*)(xp + 8);
  float4 a3 = *(const float4*)(xp + 12);
  uint4  bA = *(const uint4*)(wp);
  uint4  bB = *(const uint4*)(wp + 8);

  const int arow0 = (wm * 64 + lm) * 40 + quad * 8;
  const int brow0 = (wn * 64 + lm) * 40 + quad * 8;

  #pragma unroll 1
  for (int it = 0; it < 32; ++it) {
    __syncthreads();
    uint4 p0, p1;
    p0.x = f2bf2(a0.x, a0.y); p0.y = f2bf2(a0.z, a0.w);
    p0.z = f2bf2(a1.x, a1.y); p0.w = f2bf2(a1.z, a1.w);
    p1.x = f2bf2(a2.x, a2.y); p1.y = f2bf2(a2.z, a2.w);
    p1.z = f2bf2(a3.x, a3.y); p1.w = f2bf2(a3.z, a3.w);
    *(uint4*)&Asl[sbase]     = p0;
    *(uint4*)&Asl[sbase + 8] = p1;
    *(uint4*)&Bsl[sbase]     = bA;
    *(uint4*)&Bsl[sbase + 8] = bB;
    __syncthreads();

    if (it < 31) {   // prefetch next K-slice; latency hides under the MFMAs
      const float* xn = xp + (it + 1) * 32;
      a0 = *(const float4*)(xn + 0);
      a1 = *(const float4*)(xn + 4);
      a2 = *(const float4*)(xn + 8);
      a3 = *(const float4*)(xn + 12);
      const unsigned short* wn2 = wp + (it + 1) * 32;
      bA = *(const uint4*)(wn2);
      bB = *(const uint4*)(wn2 + 8);
    }

    bf16x8 af[4], bfr[4];
    #pragma unroll
    for (int i = 0; i < 4; ++i) af[i]  = *(const bf16x8*)&Asl[arow0 + i * 16 * 40];
    #pragma unroll
    for (int j = 0; j < 4; ++j) bfr[j] = *(const bf16x8*)&Bsl[brow0 + j * 16 * 40];

    #pragma unroll
    for (int i = 0; i < 4; ++i)
      #pragma unroll
      for (int j = 0; j < 4; ++j)
        acc[i][j] = __builtin_amdgcn_mfma_f32_16x16x32_bf16(af[i], bfr[j], acc[i][j], 0, 0, 0);
  }

  // epilogue: D[row=(lane>>4)*4+reg][col=lane&15] per 16x16 tile; bias fused
  #pragma unroll
  for (int j = 0; j < 4; ++j) {
    const int gc = n0 + wn * 64 + j * 16 + lm;
    const float bias = 0.5f * (b_in[gc] + b_out[gc]) + b_root[gc];
    #pragma unroll
    for (int i = 0; i < 4; ++i) {
      const int gr = m0 + wm * 64 + i * 16 + quad * 4;
      float* yp = Y + (size_t)gr * Ncols + gc;
      #pragma unroll
      for (int r = 0; r < 4; ++r)
        yp[(size_t)r * Ncols] = acc[i][j][r] + bias;
    }
  }
}

// ---------------------------------------------------------------------------
extern "C" void kernel_launch(void* const* d_in, const int* in_sizes, int n_in,
                              void* d_out, int out_size, void* d_ws, size_t ws_size,
                              hipStream_t stream)
{
  const float* x      = (const float*)d_in[0];
  // d_in[1] = At : dead input (ChebConv K=1 -> no neighbor aggregation)
  const float* W_in   = (const float*)d_in[2];
  const float* b_in   = (const float*)d_in[3];
  const float* W_out  = (const float*)d_in[4];
  const float* b_out  = (const float*)d_in[5];
  const float* W_root = (const float*)d_in[6];
  const float* b_root = (const float*)d_in[7];
  float* y = (float*)d_out;

  unsigned short* Wt = (unsigned short*)d_ws;   // 512*1024 bf16 = 1 MiB

  combine_w<<<dim3(512), dim3(256), 0, stream>>>(W_in, W_out, W_root, Wt);
  gemm_fused<<<dim3(512), dim3(256), 0, stream>>>(x, Wt, b_in, b_out, b_root, y);
}

// Round 2
// 155.007 us; speedup vs baseline: 1.0045x; 1.0045x over previous
//
#include <hip/hip_runtime.h>
#include <stdint.h>

static constexpr int Mrows = 16384;   // B*N = 64*256
static constexpr int Kdim  = 1024;    // L
static constexpr int Ncols = 512;     // OUT

typedef __attribute__((ext_vector_type(8))) short bf16x8;
typedef __attribute__((ext_vector_type(4))) float f32x4;

__device__ __forceinline__ unsigned short f2bf(float f) {
  unsigned u = __builtin_bit_cast(unsigned, f);
  u += 0x7FFFu + ((u >> 16) & 1u);          // RNE
  return (unsigned short)(u >> 16);
}
__device__ __forceinline__ unsigned f2bf2(float lo, float hi) {
  unsigned ul = __builtin_bit_cast(unsigned, lo);
  unsigned uh = __builtin_bit_cast(unsigned, hi);
  ul += 0x7FFFu + ((ul >> 16) & 1u);
  uh += 0x7FFFu + ((uh >> 16) & 1u);
  return (ul >> 16) | (uh & 0xFFFF0000u);
}

// async global->LDS, 16B per lane; LDS dest = uniform base + lane*16
__device__ __forceinline__ void gl2lds16(const void* g, void* l) {
  __builtin_amdgcn_global_load_lds(
      (const __attribute__((address_space(1))) void*)g,
      (__attribute__((address_space(3))) void*)l, 16, 0, 0);
}

// ---------------------------------------------------------------------------
// prep: blocks [0,8192)  : Xbf = bf16(x)            (8 floats / thread)
//       blocks [8192, +512): Wt[n][k] = bf16(0.5*(W_in+W_out)+W_root)^T
// ---------------------------------------------------------------------------
__global__ __launch_bounds__(256) void prep(
    const float* __restrict__ x,
    const float* __restrict__ Win, const float* __restrict__ Wout,
    const float* __restrict__ Wroot,
    unsigned short* __restrict__ Xbf, unsigned short* __restrict__ Wt)
{
  const int bid = blockIdx.x;
  const int t = threadIdx.x;
  if (bid < 8192) {
    const size_t base = ((size_t)bid * 256 + t) * 8;   // 8192*256*8 = 16,777,216
    const float4 v0 = *(const float4*)(x + base);
    const float4 v1 = *(const float4*)(x + base + 4);
    uint4 p;
    p.x = f2bf2(v0.x, v0.y); p.y = f2bf2(v0.z, v0.w);
    p.z = f2bf2(v1.x, v1.y); p.w = f2bf2(v1.z, v1.w);
    *(uint4*)(Xbf + base) = p;
  } else {
    __shared__ unsigned short lds[32 * 36];
    const int b2 = bid - 8192;
    const int tk0 = (b2 & 31) * 32;          // 1024/32 = 32 K-tiles
    const int tn0 = (b2 >> 5) * 32;          // 512/32  = 16 N-tiles
    {
      const int k  = t >> 3;                 // 0..31
      const int nq = (t & 7) * 4;            // 0,4,..,28
      const int gi = (tk0 + k) * Ncols + tn0 + nq;
      const float4 wi = *(const float4*)(Win + gi);
      const float4 wo = *(const float4*)(Wout + gi);
      const float4 wr = *(const float4*)(Wroot + gi);
      lds[(nq + 0) * 36 + k] = f2bf(0.5f * (wi.x + wo.x) + wr.x);
      lds[(nq + 1) * 36 + k] = f2bf(0.5f * (wi.y + wo.y) + wr.y);
      lds[(nq + 2) * 36 + k] = f2bf(0.5f * (wi.z + wo.z) + wr.z);
      lds[(nq + 3) * 36 + k] = f2bf(0.5f * (wi.w + wo.w) + wr.w);
    }
    __syncthreads();
    {
      const int n  = t >> 3;                 // 0..31
      const int k8 = (t & 7) * 4;            // 0,4,..,28
      const ushort4 v = *(const ushort4*)&lds[n * 36 + k8];
      *(ushort4*)(Wt + (size_t)(tn0 + n) * Kdim + tk0 + k8) = v;
    }
  }
}

// ---------------------------------------------------------------------------
// gemm: Y[16384][512] = Xbf @ Wt^T + bias.  128x128 tile, BK=32, 4 waves 2x2,
// each wave 64x64 (4x4 mfma_f32_16x16x32_bf16). Staging via global_load_lds
// width=16 (no VGPR round-trip). LDS layout [row][k] unpadded (8 KB/tile);
// 16B slot s of row r holds global chunk s^((r>>1)&3) -- the swizzle is done
// on the per-lane GLOBAL address, so lane->ldsbase+lane*16 stays contiguous.
// Fragment ds_read_b128 then spreads 16 rows across all 32 banks.
// ---------------------------------------------------------------------------
__global__ __launch_bounds__(256, 2) void gemm_bf16(
    const unsigned short* __restrict__ Xbf, const unsigned short* __restrict__ Wt,
    const float* __restrict__ b_in, const float* __restrict__ b_out,
    const float* __restrict__ b_root, float* __restrict__ Y)
{
  __shared__ __attribute__((aligned(16))) short As[128 * 32];
  __shared__ __attribute__((aligned(16))) short Bs[128 * 32];

  const int bid = blockIdx.x;
  const int m0 = (bid & 127) * 128;
  const int n0 = (bid >> 7) * 128;

  const int t    = threadIdx.x;
  const int lane = t & 63;
  const int w    = t >> 6;
  const int wm   = w >> 1;
  const int wn   = w & 1;
  const int quad = lane >> 4;
  const int lm   = lane & 15;

  // --- staging addresses: each wave covers 32 rows of A and 32 rows of B
  //     (2 instructions each, 16 rows / 1 KB per instruction)
  const int sr = lane >> 2;                  // row within 16-row group
  const int ss = lane & 3;                   // LDS 16B slot within row
  const int sc = ss ^ ((sr >> 1) & 3);       // global chunk fetched into it
  const unsigned short* gA = Xbf + (size_t)(m0 + w * 32 + sr) * Kdim + sc * 8;
  const unsigned short* gB = Wt  + (size_t)(n0 + w * 32 + sr) * Kdim + sc * 8;
  short* const lA0 = &As[(w * 32) * 32];
  short* const lA1 = &As[(w * 32 + 16) * 32];
  short* const lB0 = &Bs[(w * 32) * 32];
  short* const lB1 = &Bs[(w * 32 + 16) * 32];
  const int rowK = 16 * Kdim;                // +16 rows in global

  // --- fragment addresses (shorts): row ra = wm*64+i*16+lm, chunk quad lives
  //     at slot quad^((ra>>1)&3); (ra>>1)&3 == (lm>>1)&3 for all i.
  const int slot = quad ^ ((lm >> 1) & 3);
  const int aoff = (wm * 64 + lm) * 32 + slot * 8;
  const int boff = (wn * 64 + lm) * 32 + slot * 8;

  f32x4 acc[4][4] = {};

  #pragma unroll 1
  for (int it = 0; it < 32; ++it) {
    const unsigned short* ga = gA + it * 32;
    const unsigned short* gb = gB + it * 32;
    gl2lds16(ga,        lA0);
    gl2lds16(ga + rowK, lA1);
    gl2lds16(gb,        lB0);
    gl2lds16(gb + rowK, lB1);
    __syncthreads();                         // vmcnt(0)+barrier: tile visible

    bf16x8 af[4], bfr[4];
    #pragma unroll
    for (int i = 0; i < 4; ++i) af[i]  = *(const bf16x8*)&As[aoff + i * 16 * 32];
    #pragma unroll
    for (int j = 0; j < 4; ++j) bfr[j] = *(const bf16x8*)&Bs[boff + j * 16 * 32];

    #pragma unroll
    for (int i = 0; i < 4; ++i)
      #pragma unroll
      for (int j = 0; j < 4; ++j)
        acc[i][j] = __builtin_amdgcn_mfma_f32_16x16x32_bf16(af[i], bfr[j], acc[i][j], 0, 0, 0);

    __syncthreads();                         // frags consumed before overwrite
  }

  // epilogue: D[row=(lane>>4)*4+reg][col=lane&15] per 16x16 tile; bias fused
  #pragma unroll
  for (int j = 0; j < 4; ++j) {
    const int gc = n0 + wn * 64 + j * 16 + lm;
    const float bias = 0.5f * (b_in[gc] + b_out[gc]) + b_root[gc];
    #pragma unroll
    for (int i = 0; i < 4; ++i) {
      const int gr = m0 + wm * 64 + i * 16 + quad * 4;
      float* yp = Y + (size_t)gr * Ncols + gc;
      #pragma unroll
      for (int r = 0; r < 4; ++r)
        yp[(size_t)r * Ncols] = acc[i][j][r] + bias;
    }
  }
}

// ---------------------------------------------------------------------------
extern "C" void kernel_launch(void* const* d_in, const int* in_sizes, int n_in,
                              void* d_out, int out_size, void* d_ws, size_t ws_size,
                              hipStream_t stream)
{
  const float* x      = (const float*)d_in[0];
  // d_in[1] = At : dead input (ChebConv K=1 -> no neighbor aggregation)
  const float* W_in   = (const float*)d_in[2];
  const float* b_in   = (const float*)d_in[3];
  const float* W_out  = (const float*)d_in[4];
  const float* b_out  = (const float*)d_in[5];
  const float* W_root = (const float*)d_in[6];
  const float* b_root = (const float*)d_in[7];
  float* y = (float*)d_out;

  unsigned short* Xbf = (unsigned short*)d_ws;                    // 32 MiB
  unsigned short* Wt  = (unsigned short*)d_ws + (size_t)Mrows * Kdim; // 1 MiB

  prep<<<dim3(8192 + 512), dim3(256), 0, stream>>>(x, W_in, W_out, W_root, Xbf, Wt);
  gemm_bf16<<<dim3(512), dim3(256), 0, stream>>>(Xbf, Wt, b_in, b_out, b_root, y);
}